// Round 8
// baseline (220.706 us; speedup 1.0000x reference)
//
#include <hip/hip_runtime.h>
#include <math.h>

typedef __attribute__((ext_vector_type(8))) short short8;
typedef __attribute__((ext_vector_type(4))) float f32x4;
typedef unsigned short ushort_t;
typedef unsigned int uint_t;

#define DIM 64
#define NE 1024
#define NROW 65536
#define NELEM (NROW * DIM)  // 4194304
#define MARGIN 0.1f

// ws layout (bytes):
#define OFF_BPACK 0        // 256 KB: bf16-split embed, MFMA B-frag order
#define OFF_CN 262144      // 4 KB: ||e_j||^2 fp32
#define OFF_ET 266240      // 256 KB: embed^T fp32 [code][d]
#define OFF_ACC 528384     // 8 B: f64 loss accumulator
#define OFF_FCNT 528392    // 4 B: flag count
#define OFF_DONE 528396    // 4 B: fixup completion counter
#define OFF_FLAGS 528400   // 256 KB: flagged row ids

__device__ __forceinline__ ushort_t f2bf(float f) {
  uint_t u = __float_as_uint(f);
  uint_t r = (u + 0x7FFFu + ((u >> 16) & 1u)) >> 16;
  return (ushort_t)r;
}

// ---------------- prepack: embed -> {B-frag bf16 hi/lo, colnorms, embed^T}; zero accumulators
__global__ void prepack_kernel(const float* __restrict__ embed, ushort_t* __restrict__ bp,
                               float* __restrict__ cn, float* __restrict__ et,
                               double* __restrict__ acc, int* __restrict__ fcnt,
                               int* __restrict__ done) {
  __shared__ float nsum[8][32];
  const int tid = threadIdx.x;
  if (blockIdx.x == 0 && tid == 0) {
    acc[0] = 0.0;
    fcnt[0] = 0;
    done[0] = 0;
  }
  const int cl_ = tid & 31;   // code within block
  const int dg = tid >> 5;    // 0..7 dim group
  const int code = blockIdx.x * 32 + cl_;
  const int c16 = code >> 4, cl = code & 15;

  float vals[8];
  float nrm = 0.f;
#pragma unroll
  for (int jd = 0; jd < 8; ++jd) {
    int d = dg * 8 + jd;
    float e = embed[d * NE + code];
    vals[jd] = e;
    nrm = fmaf(e, e, nrm);
  }
  nsum[dg][cl_] = nrm;

  float4 a = {vals[0], vals[1], vals[2], vals[3]};
  float4 b4 = {vals[4], vals[5], vals[6], vals[7]};
  *reinterpret_cast<float4*>(&et[(size_t)code * 64 + dg * 8]) = a;
  *reinterpret_cast<float4*>(&et[(size_t)code * 64 + dg * 8 + 4]) = b4;

#pragma unroll
  for (int jd = 0; jd < 8; ++jd) {
    int d = dg * 8 + jd;
    ushort_t h = f2bf(vals[jd]);
    float hf = __uint_as_float((uint_t)h << 16);
    ushort_t lo = f2bf(vals[jd] - hf);
    int lane = cl + ((d >> 3) & 3) * 16;
    int j = d & 7;
    int kk = d >> 5;
    bp[(((c16 * 4) + kk) * 64 + lane) * 8 + j] = h;       // hi sections 0,1
    bp[(((c16 * 4) + 2 + kk) * 64 + lane) * 8 + j] = lo;  // lo sections 2,3
  }
  __syncthreads();
  if (tid < 32) {
    float s = 0.f;
#pragma unroll
    for (int w = 0; w < 8; ++w) s += nsum[w][tid];
    cn[blockIdx.x * 32 + tid] = s;
  }
}

// ---------------- score: barrier-free per-wave pipeline, split-bf16 MFMA, fused gather
__launch_bounds__(128, 3)
__global__ void score_kernel(const float* __restrict__ input, const ushort_t* __restrict__ bp,
                             const float* __restrict__ cn, const float* __restrict__ et,
                             float* __restrict__ out, double* __restrict__ acc,
                             int* __restrict__ fcnt, int* __restrict__ flags) {
  __shared__ short8 Bs[2][3][4][64];  // [wave][buf][k][lane] : 12 KB per wave, private ring
  __shared__ float cns[NE];
  __shared__ double wredd[2];

  const int tid = threadIdx.x;
  const int wave = tid >> 6, lane = tid & 63;
  const int col = lane & 15, g = lane >> 4;
  const long rowbase = (long)blockIdx.x * 64 + wave * 32;  // 2 row-tiles of 16 per wave

  // A fragments first (their vmcnt retires before the loop's counted waits)
  short8 ah[2][2], al[2][2];
#pragma unroll
  for (int rt = 0; rt < 2; ++rt)
#pragma unroll
    for (int kk = 0; kk < 2; ++kk) {
      const float* xp = &input[(size_t)(rowbase + rt * 16 + col) * 64 + kk * 32 + g * 8];
      float4 x0 = *reinterpret_cast<const float4*>(xp);
      float4 x1 = *reinterpret_cast<const float4*>(xp + 4);
      float xs[8] = {x0.x, x0.y, x0.z, x0.w, x1.x, x1.y, x1.z, x1.w};
#pragma unroll
      for (int j = 0; j < 8; ++j) {
        ushort_t h = f2bf(xs[j]);
        ah[rt][kk][j] = (short)h;
        float hf = __uint_as_float((uint_t)h << 16);
        al[rt][kk][j] = (short)f2bf(xs[j] - hf);
      }
    }

  // stage colnorms to LDS (ds_read in loop -> lgkmcnt, not vmcnt)
#pragma unroll
  for (int it = 0; it < 2; ++it) {
    int o = it * 512 + tid * 4;
    *reinterpret_cast<float4*>(&cns[o]) = *reinterpret_cast<const float4*>(&cn[o]);
  }

#define STAGE(b, cc)                                                                         \
  {                                                                                          \
    const char* gsrc = (const char*)bp + (cc) * 4096 + lane * 16;                            \
    char* ldst = (char*)&Bs[wave][(b)][0][0];                                                \
    __builtin_amdgcn_global_load_lds((const __attribute__((address_space(1))) void*)(gsrc),  \
                                     (__attribute__((address_space(3))) void*)(ldst), 16, 0, 0); \
    __builtin_amdgcn_global_load_lds(                                                        \
        (const __attribute__((address_space(1))) void*)(gsrc + 1024),                        \
        (__attribute__((address_space(3))) void*)(ldst + 1024), 16, 0, 0);                   \
    __builtin_amdgcn_global_load_lds(                                                        \
        (const __attribute__((address_space(1))) void*)(gsrc + 2048),                        \
        (__attribute__((address_space(3))) void*)(ldst + 2048), 16, 0, 0);                   \
    __builtin_amdgcn_global_load_lds(                                                        \
        (const __attribute__((address_space(1))) void*)(gsrc + 3072),                        \
        (__attribute__((address_space(3))) void*)(ldst + 3072), 16, 0, 0);                   \
  }

  STAGE(0, 0);
  STAGE(1, 1);

  float v1[2][4], v2[2][4];
  int i1[2][4];
#pragma unroll
  for (int rt = 0; rt < 2; ++rt)
#pragma unroll
    for (int r = 0; r < 4; ++r) {
      v1[rt][r] = -INFINITY;
      v2[rt][r] = -INFINITY;
      i1[rt][r] = 0;
    }

  __syncthreads();  // cns visible to both waves (also drains the 2 staged chunks; one-time)

  int buf = 0, sbuf = 2;
#pragma unroll 1
  for (int c = 0; c < 64; ++c) {
    // own stage(c) landed. Steady state keeps one full chunk (4 loads) in flight.
    if (c < 63) {
      asm volatile("s_waitcnt vmcnt(4)" ::: "memory");
    } else {
      asm volatile("s_waitcnt vmcnt(0)" ::: "memory");
    }
    __builtin_amdgcn_sched_barrier(0);
    if (c < 62) STAGE(sbuf, c + 2);

    short8 bh0 = Bs[wave][buf][0][lane];
    short8 bh1 = Bs[wave][buf][1][lane];
    short8 bl0 = Bs[wave][buf][2][lane];
    short8 bl1 = Bs[wave][buf][3][lane];
    float cnv = cns[c * 16 + col];

    f32x4 accA = {0.f, 0.f, 0.f, 0.f};
    f32x4 accB = {0.f, 0.f, 0.f, 0.f};
    accA = __builtin_amdgcn_mfma_f32_16x16x32_bf16(ah[0][0], bh0, accA, 0, 0, 0);
    accB = __builtin_amdgcn_mfma_f32_16x16x32_bf16(ah[1][0], bh0, accB, 0, 0, 0);
    accA = __builtin_amdgcn_mfma_f32_16x16x32_bf16(ah[0][1], bh1, accA, 0, 0, 0);
    accB = __builtin_amdgcn_mfma_f32_16x16x32_bf16(ah[1][1], bh1, accB, 0, 0, 0);
    accA = __builtin_amdgcn_mfma_f32_16x16x32_bf16(al[0][0], bh0, accA, 0, 0, 0);
    accB = __builtin_amdgcn_mfma_f32_16x16x32_bf16(al[1][0], bh0, accB, 0, 0, 0);
    accA = __builtin_amdgcn_mfma_f32_16x16x32_bf16(al[0][1], bh1, accA, 0, 0, 0);
    accB = __builtin_amdgcn_mfma_f32_16x16x32_bf16(al[1][1], bh1, accB, 0, 0, 0);
    accA = __builtin_amdgcn_mfma_f32_16x16x32_bf16(ah[0][0], bl0, accA, 0, 0, 0);
    accB = __builtin_amdgcn_mfma_f32_16x16x32_bf16(ah[1][0], bl0, accB, 0, 0, 0);
    accA = __builtin_amdgcn_mfma_f32_16x16x32_bf16(ah[0][1], bl1, accA, 0, 0, 0);
    accB = __builtin_amdgcn_mfma_f32_16x16x32_bf16(ah[1][1], bl1, accB, 0, 0, 0);

    const int code = c * 16 + col;
#pragma unroll
    for (int r = 0; r < 4; ++r) {
      float v = fmaf(2.f, accA[r], -cnv);
      v2[0][r] = __builtin_amdgcn_fmed3f(v, v1[0][r], v2[0][r]);
      bool gt = v > v1[0][r];
      i1[0][r] = gt ? code : i1[0][r];
      v1[0][r] = fmaxf(v1[0][r], v);
    }
#pragma unroll
    for (int r = 0; r < 4; ++r) {
      float v = fmaf(2.f, accB[r], -cnv);
      v2[1][r] = __builtin_amdgcn_fmed3f(v, v1[1][r], v2[1][r]);
      bool gt = v > v1[1][r];
      i1[1][r] = gt ? code : i1[1][r];
      v1[1][r] = fmaxf(v1[1][r], v);
    }
    buf = (buf == 2) ? 0 : buf + 1;
    sbuf = (sbuf == 2) ? 0 : sbuf + 1;
  }
#undef STAGE

  // epilogue: merge top-2 across 16 col-lanes; gather hard codes; write out0+idx; loss
  double lsum = 0.0;
#pragma unroll
  for (int rt = 0; rt < 2; ++rt)
#pragma unroll
    for (int r = 0; r < 4; ++r) {
      float bv1 = v1[rt][r], bv2 = v2[rt][r];
      int bidx = i1[rt][r];
#pragma unroll
      for (int off = 1; off <= 8; off <<= 1) {
        float ov1 = __shfl_xor(bv1, off);
        int oi = __shfl_xor(bidx, off);
        float ov2 = __shfl_xor(bv2, off);
        bool take = (ov1 > bv1) || (ov1 == bv1 && oi < bidx);
        float nv2 = take ? fmaxf(bv1, ov2) : fmaxf(bv2, ov1);
        bv1 = take ? ov1 : bv1;
        bidx = take ? oi : bidx;
        bv2 = nv2;
      }
      long row = rowbase + rt * 16 + g * 4 + r;
      float4 h = *reinterpret_cast<const float4*>(&et[(size_t)bidx * 64 + col * 4]);
      float4 x = *reinterpret_cast<const float4*>(&input[(size_t)row * 64 + col * 4]);
      *reinterpret_cast<float4*>(&out[(size_t)row * 64 + col * 4]) = h;
      float d0 = h.x - x.x, d1 = h.y - x.y, d2 = h.z - x.z, d3 = h.w - x.w;
      lsum += (double)(d0 * d0 + d1 * d1 + d2 * d2 + d3 * d3);
      if (col == 0) {
        out[NELEM + row] = (float)bidx;
        if (bv1 - bv2 < MARGIN) {
          int p = atomicAdd(fcnt, 1);
          flags[p] = (int)row;
        }
      }
    }

#pragma unroll
  for (int off = 1; off <= 32; off <<= 1) lsum += __shfl_xor(lsum, off);
  if (lane == 0) wredd[wave] = lsum;
  __syncthreads();
  if (tid == 0) unsafeAtomicAdd(acc, wredd[0] + wredd[1]);
}

// ---------------- fixup: exact f64 argmax for flagged rows; repair idx/out0/loss; finalize
__global__ void fixup_kernel(const float* __restrict__ input, const float* __restrict__ embed,
                             const float* __restrict__ et, float* __restrict__ out,
                             double* __restrict__ acc, const int* __restrict__ fcnt,
                             const int* __restrict__ flags, int* __restrict__ done) {
  __shared__ float Xs[8][64];
  __shared__ double Wv[4][8];
  __shared__ int Wi[4][8];
  __shared__ int NewI[8], OldI[8], Rw[8];
  const int tid = threadIdx.x;
  const int lane = tid & 63, wv = tid >> 6;
  const int count = *fcnt;

  for (int base = blockIdx.x * 8; base < count; base += gridDim.x * 8) {
    __syncthreads();  // previous pass done with shared
    if (tid < 8) {
      int p = base + tid;
      int r = (p < count) ? flags[p] : flags[count - 1];
      Rw[tid] = r;
      OldI[tid] = (int)out[NELEM + r];
    }
    __syncthreads();
    if (tid < 128) {
      int r8 = tid >> 4, seg = (tid & 15) * 4;
      *reinterpret_cast<float4*>(&Xs[r8][seg]) =
          *reinterpret_cast<const float4*>(&input[(size_t)Rw[r8] * 64 + seg]);
    }
    __syncthreads();

    const int j0 = tid * 4;
    double dot[8][4];
    double nrm[4];
#pragma unroll
    for (int r = 0; r < 8; ++r)
#pragma unroll
      for (int cc = 0; cc < 4; ++cc) dot[r][cc] = 0.0;
#pragma unroll
    for (int cc = 0; cc < 4; ++cc) nrm[cc] = 0.0;

    for (int d = 0; d < 64; ++d) {
      float4 e4 = *reinterpret_cast<const float4*>(&embed[d * NE + j0]);
      double ev[4] = {(double)e4.x, (double)e4.y, (double)e4.z, (double)e4.w};
#pragma unroll
      for (int cc = 0; cc < 4; ++cc) nrm[cc] = fma(ev[cc], ev[cc], nrm[cc]);
#pragma unroll
      for (int r = 0; r < 8; ++r) {
        double xr = (double)Xs[r][d];
#pragma unroll
        for (int cc = 0; cc < 4; ++cc) dot[r][cc] = fma(xr, ev[cc], dot[r][cc]);
      }
    }

#pragma unroll
    for (int r = 0; r < 8; ++r) {
      double bv = -1e300;
      int bi = 0;
#pragma unroll
      for (int cc = 0; cc < 4; ++cc) {
        double t = 2.0 * dot[r][cc] - nrm[cc];
        if (t > bv) {
          bv = t;
          bi = j0 + cc;
        }
      }
#pragma unroll
      for (int off = 1; off <= 32; off <<= 1) {
        double ob = __shfl_xor(bv, off);
        int oi = __shfl_xor(bi, off);
        if (ob > bv || (ob == bv && oi < bi)) {
          bv = ob;
          bi = oi;
        }
      }
      if (lane == 0) {
        Wv[wv][r] = bv;
        Wi[wv][r] = bi;
      }
    }
    __syncthreads();
    if (tid < 8) {
      double bv = Wv[0][tid];
      int bi = Wi[0][tid];
#pragma unroll
      for (int w = 1; w < 4; ++w) {
        double ob = Wv[w][tid];
        int oi = Wi[w][tid];
        if (ob > bv || (ob == bv && oi < bi)) {
          bv = ob;
          bi = oi;
        }
      }
      NewI[tid] = bi;
      if (base + tid < count && bi != OldI[tid]) out[NELEM + Rw[tid]] = (float)bi;
    }
    __syncthreads();
    if (tid < 128) {
      int r8 = tid >> 4, seg = (tid & 15) * 4;
      if (base + r8 < count && NewI[r8] != OldI[r8]) {
        float4 hn = *reinterpret_cast<const float4*>(&et[(size_t)NewI[r8] * 64 + seg]);
        float4 ho = *reinterpret_cast<const float4*>(&et[(size_t)OldI[r8] * 64 + seg]);
        float4 x = *reinterpret_cast<const float4*>(&Xs[r8][seg]);
        *reinterpret_cast<float4*>(&out[(size_t)Rw[r8] * 64 + seg]) = hn;
        float n0 = hn.x - x.x, n1 = hn.y - x.y, n2 = hn.z - x.z, n3 = hn.w - x.w;
        float o0 = ho.x - x.x, o1 = ho.y - x.y, o2 = ho.z - x.z, o3 = ho.w - x.w;
        double delta = (double)(n0 * n0 + n1 * n1 + n2 * n2 + n3 * n3) -
                       (double)(o0 * o0 + o1 * o1 + o2 * o2 + o3 * o3);
        unsafeAtomicAdd(acc, delta);
      }
    }
  }

  // finalize: last block to finish writes the two scalars
  __syncthreads();  // all this block's atomics issued & drained at the barrier
  if (tid == 0) {
    __threadfence();
    int prev = atomicAdd(done, 1);
    if (prev == (int)gridDim.x - 1) {
      double v = unsafeAtomicAdd(acc, 0.0);  // atomic read at coherence point
      float f = (float)(v / (double)NELEM);
      out[NELEM + NROW + 0] = f;  // diff
      out[NELEM + NROW + 1] = f;  // embed_loss (== diff to ~1e-7 rel)
    }
  }
}

extern "C" void kernel_launch(void* const* d_in, const int* in_sizes, int n_in,
                              void* d_out, int out_size, void* d_ws, size_t ws_size,
                              hipStream_t stream) {
  const float* input = (const float*)d_in[0];
  const float* embed = (const float*)d_in[1];
  float* out = (float*)d_out;
  char* ws = (char*)d_ws;
  ushort_t* bp = (ushort_t*)(ws + OFF_BPACK);
  float* cn = (float*)(ws + OFF_CN);
  float* et = (float*)(ws + OFF_ET);
  double* acc = (double*)(ws + OFF_ACC);
  int* fcnt = (int*)(ws + OFF_FCNT);
  int* done = (int*)(ws + OFF_DONE);
  int* flags = (int*)(ws + OFF_FLAGS);

  prepack_kernel<<<32, 256, 0, stream>>>(embed, bp, cn, et, acc, fcnt, done);
  score_kernel<<<NROW / 64, 128, 0, stream>>>(input, bp, cn, et, out, acc, fcnt, flags);
  fixup_kernel<<<64, 256, 0, stream>>>(input, embed, et, out, acc, fcnt, flags, done);
}

// Round 9
// 138.317 us; speedup vs baseline: 1.5957x; 1.5957x over previous
//
#include <hip/hip_runtime.h>
#include <math.h>

typedef __attribute__((ext_vector_type(8))) short short8;
typedef __attribute__((ext_vector_type(4))) float f32x4;
typedef unsigned short ushort_t;
typedef unsigned int uint_t;

#define DIM 64
#define NE 1024
#define NROW 65536
#define NELEM (NROW * DIM)  // 4194304
#define MARGIN 0.02f

// ws layout (bytes):
#define OFF_BPACK 0        // 256 KB: bf16-split embed, MFMA B-frag order
#define OFF_CN 262144      // 4 KB: ||e_j||^2 fp32
#define OFF_ET 266240      // 256 KB: embed^T fp32 [code][d]
#define OFF_ACC 528384     // 1 KB: 8 f64 loss slots, stride 128 B
#define OFF_FCNT 529408    // 4 B: flag count
#define OFF_DONE 529412    // 4 B: fixup completion counter
#define OFF_FLAGS 529424   // 256 KB: flagged row ids

__device__ __forceinline__ ushort_t f2bf(float f) {
  uint_t u = __float_as_uint(f);
  uint_t r = (u + 0x7FFFu + ((u >> 16) & 1u)) >> 16;
  return (ushort_t)r;
}

// ---------------- prepack: embed -> {B-frag bf16 hi/lo, colnorms, embed^T}; zero accumulators
__global__ void prepack_kernel(const float* __restrict__ embed, ushort_t* __restrict__ bp,
                               float* __restrict__ cn, float* __restrict__ et,
                               double* __restrict__ acc, int* __restrict__ fcnt,
                               int* __restrict__ done) {
  __shared__ float nsum[8][32];
  const int tid = threadIdx.x;
  if (blockIdx.x == 0) {
    if (tid < 8) acc[tid * 16] = 0.0;
    if (tid == 0) {
      fcnt[0] = 0;
      done[0] = 0;
    }
  }
  const int cl_ = tid & 31;  // code within block
  const int dg = tid >> 5;   // 0..7 dim group
  const int code = blockIdx.x * 32 + cl_;
  const int c16 = code >> 4, cl = code & 15;
  const int lane = cl + (dg & 3) * 16;  // constant per thread
  const int kk = dg >> 2;               // constant per thread

  float vals[8];
  float nrm = 0.f;
#pragma unroll
  for (int jd = 0; jd < 8; ++jd) {
    int d = dg * 8 + jd;
    float e = embed[d * NE + code];
    vals[jd] = e;
    nrm = fmaf(e, e, nrm);
  }
  nsum[dg][cl_] = nrm;

  float4 a = {vals[0], vals[1], vals[2], vals[3]};
  float4 b4 = {vals[4], vals[5], vals[6], vals[7]};
  *reinterpret_cast<float4*>(&et[(size_t)code * 64 + dg * 8]) = a;
  *reinterpret_cast<float4*>(&et[(size_t)code * 64 + dg * 8 + 4]) = b4;

  short8 hv, lv;
#pragma unroll
  for (int jd = 0; jd < 8; ++jd) {
    ushort_t h = f2bf(vals[jd]);
    float hf = __uint_as_float((uint_t)h << 16);
    hv[jd] = (short)h;
    lv[jd] = (short)f2bf(vals[jd] - hf);
  }
  *reinterpret_cast<short8*>(&bp[((size_t)(c16 * 4 + kk) * 64 + lane) * 8]) = hv;
  *reinterpret_cast<short8*>(&bp[((size_t)(c16 * 4 + 2 + kk) * 64 + lane) * 8]) = lv;

  __syncthreads();
  if (tid < 32) {
    float s = 0.f;
#pragma unroll
    for (int w = 0; w < 8; ++w) s += nsum[w][tid];
    cn[blockIdx.x * 32 + tid] = s;
  }
}

// ---------------- score: 1 wave / 32 rows, register-staged B, full 4-product split-bf16
__launch_bounds__(64, 2)
__global__ void score_kernel(const float* __restrict__ input, const ushort_t* __restrict__ bp,
                             const float* __restrict__ cn, const float* __restrict__ et,
                             float* __restrict__ out, double* __restrict__ acc,
                             int* __restrict__ fcnt, int* __restrict__ flags) {
  __shared__ float cns[NE];
  const int lane = threadIdx.x;  // 0..63
  const int col = lane & 15, g = lane >> 4;
  const long rowbase = (long)blockIdx.x * 32;

  // stage colnorms to LDS (one-time)
#pragma unroll
  for (int i = 0; i < 4; ++i) {
    int o = i * 256 + lane * 4;
    *reinterpret_cast<float4*>(&cns[o]) = *reinterpret_cast<const float4*>(&cn[o]);
  }

  // A fragments: 32 rows in bf16 hi/lo, resident all-kernel
  short8 ah[2][2], al[2][2];
#pragma unroll
  for (int rt = 0; rt < 2; ++rt)
#pragma unroll
    for (int kk = 0; kk < 2; ++kk) {
      const float* xp = &input[(size_t)(rowbase + rt * 16 + col) * 64 + kk * 32 + g * 8];
      float4 x0 = *reinterpret_cast<const float4*>(xp);
      float4 x1 = *reinterpret_cast<const float4*>(xp + 4);
      float xs[8] = {x0.x, x0.y, x0.z, x0.w, x1.x, x1.y, x1.z, x1.w};
#pragma unroll
      for (int j = 0; j < 8; ++j) {
        ushort_t h = f2bf(xs[j]);
        ah[rt][kk][j] = (short)h;
        float hf = __uint_as_float((uint_t)h << 16);
        al[rt][kk][j] = (short)f2bf(xs[j] - hf);
      }
    }

  float v1[2][4], v2[2][4];
  int i1[2][4];
#pragma unroll
  for (int rt = 0; rt < 2; ++rt)
#pragma unroll
    for (int r = 0; r < 4; ++r) {
      v1[rt][r] = -INFINITY;
      v2[rt][r] = -INFINITY;
      i1[rt][r] = 0;
    }

  __syncthreads();  // cns staged (single wave: cheap)

  const short8* bpv = reinterpret_cast<const short8*>(bp);  // 16B granules

  short8 b0h0, b0h1, b0l0, b0l1, b1h0, b1h1, b1l0, b1l1;
#define LOADB(B, cc)                       \
  {                                        \
    b##B##h0 = bpv[(cc)*256 + lane];       \
    b##B##h1 = bpv[(cc)*256 + 64 + lane];  \
    b##B##l0 = bpv[(cc)*256 + 128 + lane]; \
    b##B##l1 = bpv[(cc)*256 + 192 + lane]; \
  }

#define COMPUTE(B, cc)                                                            \
  {                                                                               \
    float cnv = cns[(cc)*16 + col];                                               \
    f32x4 aA = {0.f, 0.f, 0.f, 0.f};                                              \
    f32x4 aB = {0.f, 0.f, 0.f, 0.f};                                              \
    aA = __builtin_amdgcn_mfma_f32_16x16x32_bf16(ah[0][0], b##B##h0, aA, 0, 0, 0); \
    aB = __builtin_amdgcn_mfma_f32_16x16x32_bf16(ah[1][0], b##B##h0, aB, 0, 0, 0); \
    aA = __builtin_amdgcn_mfma_f32_16x16x32_bf16(ah[0][1], b##B##h1, aA, 0, 0, 0); \
    aB = __builtin_amdgcn_mfma_f32_16x16x32_bf16(ah[1][1], b##B##h1, aB, 0, 0, 0); \
    aA = __builtin_amdgcn_mfma_f32_16x16x32_bf16(al[0][0], b##B##h0, aA, 0, 0, 0); \
    aB = __builtin_amdgcn_mfma_f32_16x16x32_bf16(al[1][0], b##B##h0, aB, 0, 0, 0); \
    aA = __builtin_amdgcn_mfma_f32_16x16x32_bf16(al[0][1], b##B##h1, aA, 0, 0, 0); \
    aB = __builtin_amdgcn_mfma_f32_16x16x32_bf16(al[1][1], b##B##h1, aB, 0, 0, 0); \
    aA = __builtin_amdgcn_mfma_f32_16x16x32_bf16(ah[0][0], b##B##l0, aA, 0, 0, 0); \
    aB = __builtin_amdgcn_mfma_f32_16x16x32_bf16(ah[1][0], b##B##l0, aB, 0, 0, 0); \
    aA = __builtin_amdgcn_mfma_f32_16x16x32_bf16(ah[0][1], b##B##l1, aA, 0, 0, 0); \
    aB = __builtin_amdgcn_mfma_f32_16x16x32_bf16(ah[1][1], b##B##l1, aB, 0, 0, 0); \
    aA = __builtin_amdgcn_mfma_f32_16x16x32_bf16(al[0][0], b##B##l0, aA, 0, 0, 0); \
    aB = __builtin_amdgcn_mfma_f32_16x16x32_bf16(al[1][0], b##B##l0, aB, 0, 0, 0); \
    aA = __builtin_amdgcn_mfma_f32_16x16x32_bf16(al[0][1], b##B##l1, aA, 0, 0, 0); \
    aB = __builtin_amdgcn_mfma_f32_16x16x32_bf16(al[1][1], b##B##l1, aB, 0, 0, 0); \
    const int code = (cc)*16 + col;                                               \
    _Pragma("unroll") for (int r = 0; r < 4; ++r) {                               \
      float v = fmaf(2.f, aA[r], -cnv);                                           \
      v2[0][r] = __builtin_amdgcn_fmed3f(v, v1[0][r], v2[0][r]);                  \
      bool gt = v > v1[0][r];                                                     \
      i1[0][r] = gt ? code : i1[0][r];                                            \
      v1[0][r] = fmaxf(v1[0][r], v);                                              \
    }                                                                             \
    _Pragma("unroll") for (int r = 0; r < 4; ++r) {                               \
      float v = fmaf(2.f, aB[r], -cnv);                                           \
      v2[1][r] = __builtin_amdgcn_fmed3f(v, v1[1][r], v2[1][r]);                  \
      bool gt = v > v1[1][r];                                                     \
      i1[1][r] = gt ? code : i1[1][r];                                            \
      v1[1][r] = fmaxf(v1[1][r], v);                                              \
    }                                                                             \
  }

  LOADB(0, 0);
  LOADB(1, 1);
#pragma unroll 1
  for (int c = 0; c < 64; c += 2) {
    COMPUTE(0, c);
    if (c + 2 < 64) LOADB(0, c + 2);
    COMPUTE(1, c + 1);
    if (c + 3 < 64) LOADB(1, c + 3);
  }
#undef LOADB
#undef COMPUTE

  // epilogue: merge top-2 across 16 col-lanes; gather hard codes; write out0+idx; loss
  double lsum = 0.0;
#pragma unroll
  for (int rt = 0; rt < 2; ++rt)
#pragma unroll
    for (int r = 0; r < 4; ++r) {
      float bv1 = v1[rt][r], bv2 = v2[rt][r];
      int bidx = i1[rt][r];
#pragma unroll
      for (int off = 1; off <= 8; off <<= 1) {
        float ov1 = __shfl_xor(bv1, off);
        int oi = __shfl_xor(bidx, off);
        float ov2 = __shfl_xor(bv2, off);
        bool take = (ov1 > bv1) || (ov1 == bv1 && oi < bidx);
        float nv2 = take ? fmaxf(bv1, ov2) : fmaxf(bv2, ov1);
        bv1 = take ? ov1 : bv1;
        bidx = take ? oi : bidx;
        bv2 = nv2;
      }
      long row = rowbase + rt * 16 + g * 4 + r;
      float4 h = *reinterpret_cast<const float4*>(&et[(size_t)bidx * 64 + col * 4]);
      float4 x = *reinterpret_cast<const float4*>(&input[(size_t)row * 64 + col * 4]);
      *reinterpret_cast<float4*>(&out[(size_t)row * 64 + col * 4]) = h;
      float d0 = h.x - x.x, d1 = h.y - x.y, d2 = h.z - x.z, d3 = h.w - x.w;
      lsum += (double)(d0 * d0 + d1 * d1 + d2 * d2 + d3 * d3);
      if (col == 0) {
        out[NELEM + row] = (float)bidx;
        if (bv1 - bv2 < MARGIN) {
          int p = atomicAdd(fcnt, 1);
          flags[p] = (int)row;
        }
      }
    }

#pragma unroll
  for (int off = 1; off <= 32; off <<= 1) lsum += __shfl_xor(lsum, off);
  if (lane == 0) unsafeAtomicAdd(&acc[(blockIdx.x & 7) * 16], lsum);
}

// ---------------- fixup: exact f64 argmax for flagged rows; repair idx/out0/loss; finalize
__global__ void fixup_kernel(const float* __restrict__ input, const float* __restrict__ embed,
                             const float* __restrict__ et, float* __restrict__ out,
                             double* __restrict__ acc, const int* __restrict__ fcnt,
                             const int* __restrict__ flags, int* __restrict__ done) {
  __shared__ float Xs[8][64];
  __shared__ double Wv[4][8];
  __shared__ int Wi[4][8];
  __shared__ int NewI[8], OldI[8], Rw[8];
  const int tid = threadIdx.x;
  const int lane = tid & 63, wv = tid >> 6;
  const int count = *fcnt;

  for (int base = blockIdx.x * 8; base < count; base += gridDim.x * 8) {
    __syncthreads();  // previous pass done with shared
    if (tid < 8) {
      int p = base + tid;
      int r = (p < count) ? flags[p] : flags[count - 1];
      Rw[tid] = r;
      OldI[tid] = (int)out[NELEM + r];
    }
    __syncthreads();
    if (tid < 128) {
      int r8 = tid >> 4, seg = (tid & 15) * 4;
      *reinterpret_cast<float4*>(&Xs[r8][seg]) =
          *reinterpret_cast<const float4*>(&input[(size_t)Rw[r8] * 64 + seg]);
    }
    __syncthreads();

    const int j0 = tid * 4;
    double dot[8][4];
    double nrm[4];
#pragma unroll
    for (int r = 0; r < 8; ++r)
#pragma unroll
      for (int cc = 0; cc < 4; ++cc) dot[r][cc] = 0.0;
#pragma unroll
    for (int cc = 0; cc < 4; ++cc) nrm[cc] = 0.0;

#pragma unroll 1
    for (int d = 0; d < 64; d += 4) {
      float4 e4[4];
#pragma unroll
      for (int q = 0; q < 4; ++q)
        e4[q] = *reinterpret_cast<const float4*>(&embed[(d + q) * NE + j0]);
#pragma unroll
      for (int q = 0; q < 4; ++q) {
        double ev[4] = {(double)e4[q].x, (double)e4[q].y, (double)e4[q].z, (double)e4[q].w};
#pragma unroll
        for (int cc = 0; cc < 4; ++cc) nrm[cc] = fma(ev[cc], ev[cc], nrm[cc]);
#pragma unroll
        for (int r = 0; r < 8; ++r) {
          double xr = (double)Xs[r][d + q];
#pragma unroll
          for (int cc = 0; cc < 4; ++cc) dot[r][cc] = fma(xr, ev[cc], dot[r][cc]);
        }
      }
    }

#pragma unroll
    for (int r = 0; r < 8; ++r) {
      double bv = -1e300;
      int bi = 0;
#pragma unroll
      for (int cc = 0; cc < 4; ++cc) {
        double t = 2.0 * dot[r][cc] - nrm[cc];
        if (t > bv) {
          bv = t;
          bi = j0 + cc;
        }
      }
#pragma unroll
      for (int off = 1; off <= 32; off <<= 1) {
        double ob = __shfl_xor(bv, off);
        int oi = __shfl_xor(bi, off);
        if (ob > bv || (ob == bv && oi < bi)) {
          bv = ob;
          bi = oi;
        }
      }
      if (lane == 0) {
        Wv[wv][r] = bv;
        Wi[wv][r] = bi;
      }
    }
    __syncthreads();
    if (tid < 8) {
      double bv = Wv[0][tid];
      int bi = Wi[0][tid];
#pragma unroll
      for (int w = 1; w < 4; ++w) {
        double ob = Wv[w][tid];
        int oi = Wi[w][tid];
        if (ob > bv || (ob == bv && oi < bi)) {
          bv = ob;
          bi = oi;
        }
      }
      NewI[tid] = bi;
      if (base + tid < count && bi != OldI[tid]) out[NELEM + Rw[tid]] = (float)bi;
    }
    __syncthreads();
    if (tid < 128) {
      int r8 = tid >> 4, seg = (tid & 15) * 4;
      if (base + r8 < count && NewI[r8] != OldI[r8]) {
        float4 hn = *reinterpret_cast<const float4*>(&et[(size_t)NewI[r8] * 64 + seg]);
        float4 ho = *reinterpret_cast<const float4*>(&et[(size_t)OldI[r8] * 64 + seg]);
        float4 x = *reinterpret_cast<const float4*>(&Xs[r8][seg]);
        *reinterpret_cast<float4*>(&out[(size_t)Rw[r8] * 64 + seg]) = hn;
        float n0 = hn.x - x.x, n1 = hn.y - x.y, n2 = hn.z - x.z, n3 = hn.w - x.w;
        float o0 = ho.x - x.x, o1 = ho.y - x.y, o2 = ho.z - x.z, o3 = ho.w - x.w;
        double delta = (double)(n0 * n0 + n1 * n1 + n2 * n2 + n3 * n3) -
                       (double)(o0 * o0 + o1 * o1 + o2 * o2 + o3 * o3);
        unsafeAtomicAdd(&acc[(blockIdx.x & 7) * 16], delta);
      }
    }
  }

  // finalize: last block to finish writes the two scalars
  __syncthreads();  // all this block's atomics issued before the done increment
  if (tid == 0) {
    __threadfence();
    int prev = atomicAdd(done, 1);
    if (prev == (int)gridDim.x - 1) {
      double v = 0.0;
#pragma unroll
      for (int w = 0; w < 8; ++w) v += unsafeAtomicAdd(&acc[w * 16], 0.0);
      float f = (float)(v / (double)NELEM);
      out[NELEM + NROW + 0] = f;  // diff
      out[NELEM + NROW + 1] = f;  // embed_loss (== diff to ~1e-7 rel)
    }
  }
}

extern "C" void kernel_launch(void* const* d_in, const int* in_sizes, int n_in,
                              void* d_out, int out_size, void* d_ws, size_t ws_size,
                              hipStream_t stream) {
  const float* input = (const float*)d_in[0];
  const float* embed = (const float*)d_in[1];
  float* out = (float*)d_out;
  char* ws = (char*)d_ws;
  ushort_t* bp = (ushort_t*)(ws + OFF_BPACK);
  float* cn = (float*)(ws + OFF_CN);
  float* et = (float*)(ws + OFF_ET);
  double* acc = (double*)(ws + OFF_ACC);
  int* fcnt = (int*)(ws + OFF_FCNT);
  int* done = (int*)(ws + OFF_DONE);
  int* flags = (int*)(ws + OFF_FLAGS);

  prepack_kernel<<<32, 256, 0, stream>>>(embed, bp, cn, et, acc, fcnt, done);
  score_kernel<<<NROW / 32, 64, 0, stream>>>(input, bp, cn, et, out, acc, fcnt, flags);
  fixup_kernel<<<256, 256, 0, stream>>>(input, embed, et, out, acc, fcnt, flags, done);
}